// Round 1
// 722.509 us; speedup vs baseline: 1.0244x; 1.0244x over previous
//
#include <hip/hip_runtime.h>
#include <math.h>

#define N_ATOM 2048
#define NTOK   512
#define CC     128
#define CZDIM  16
#define HH     4
#define CHD    32
#define NHID   256
#define NQB    64     // 2048 / 32 query blocks
#define R1     8      // rows per workgroup in update kernels
#define PBSTRIDE 1048576  // 64*4*32*128 floats per block's pair bias

__device__ __forceinline__ float sigm(float x) { return 1.0f / (1.0f + __expf(-x)); }

// ---------------------------------------------------------------------------
// amask_bias[l] = (sum_i a2t[l,i]*tm[i] - 1) * 1e9     (additive key mask)
__global__ __launch_bounds__(256) void k_amask(const float* __restrict__ a2t,
                                               const float* __restrict__ tm,
                                               float* __restrict__ amask) {
    int wave = threadIdx.x >> 6, lane = threadIdx.x & 63;
    int l = blockIdx.x * 4 + wave;
    float s = 0.0f;
    for (int i = lane; i < NTOK; i += 64) s += a2t[(size_t)l * NTOK + i] * tm[i];
    for (int m = 1; m < 64; m <<= 1) s += __shfl_xor(s, m);
    if (lane == 0) amask[l] = (s - 1.0f) * 1e9f;
}

// ---------------------------------------------------------------------------
// K_pb3: pair bias for ALL 3 blocks in one pass over the plm window.
// LN(plm) is block-independent; only the affine+projection differs per block.
__global__ __launch_bounds__(256) void k_pb3(const float* __restrict__ plm,
                                             const float* __restrict__ gz,
                                             const float* __restrict__ bz,
                                             const float* __restrict__ wz,
                                             float* __restrict__ pb) {
    int pid = blockIdx.x * 256 + threadIdx.x;  // 64*32*128 total
    int qb = pid >> 12;
    int qi = (pid >> 7) & 31;
    int kj = pid & 127;
    int n = qb * 32 + qi;
    int kstart = max(0, qb * 32 - 48);
    int m = kstart + kj;
    bool valid = (m < N_ATOM);
    float xn[CZDIM];
    if (valid) {
        const float4* p4 = (const float4*)(plm + ((size_t)n * N_ATOM + m) * CZDIM);
        float x[CZDIM];
#pragma unroll
        for (int i = 0; i < 4; i++) {
            float4 v = p4[i];
            x[4 * i] = v.x; x[4 * i + 1] = v.y; x[4 * i + 2] = v.z; x[4 * i + 3] = v.w;
        }
        float s = 0, s2 = 0;
#pragma unroll
        for (int c = 0; c < CZDIM; c++) { s += x[c]; s2 += x[c] * x[c]; }
        float mean = s * (1.0f / 16.0f);
        float rs = rsqrtf(s2 * (1.0f / 16.0f) - mean * mean + 1e-5f);
#pragma unroll
        for (int c = 0; c < CZDIM; c++) xn[c] = (x[c] - mean) * rs;
    }
#pragma unroll
    for (int b = 0; b < 3; b++) {
        float out[HH] = {0, 0, 0, 0};
        if (valid) {
            const float* gzb = gz + b * CZDIM;
            const float* bzb = bz + b * CZDIM;
            const float* wzb = wz + b * CZDIM * HH;
#pragma unroll
            for (int c = 0; c < CZDIM; c++) {
                float z = xn[c] * gzb[c] + bzb[c];
#pragma unroll
                for (int h = 0; h < HH; h++) out[h] += z * wzb[c * HH + h];
            }
        }
#pragma unroll
        for (int h = 0; h < HH; h++)
            pb[b * PBSTRIDE + (((qb * HH + h) * 32 + qi) << 7) + kj] = out[h];
    }
}

// ---------------------------------------------------------------------------
// Shared-memory layout + fused AdaLN/projection body used by both update kernels.
struct SmemU {
    float lna[R1][CC];   // raw a on entry to body; LN(a) after LN phase
    float sn1[R1][CC];   // LN(cl)*gs1
    float sn2[R1][CC];   // LN(cl)*gs2
    float cls[R1][CC];   // raw cl
    float aln1[R1][CC];  // AdaLN1 output (also used as g*o scratch in phase A)
    float a2s[R1][CC];   // AdaLN2 output
    float hid[R1][NHID]; // SwiGLU hidden
};

__device__ __forceinline__ void adaln_proj_body(
    SmemU& sm, int t, int n0,
    const float* __restrict__ gs1, const float* __restrict__ ws1,
    const float* __restrict__ bs1, const float* __restrict__ wsb1,
    const float* __restrict__ wq, const float* __restrict__ bq,
    const float* __restrict__ wk, const float* __restrict__ wv,
    const float* __restrict__ wg,
    const float* __restrict__ wog1, const float* __restrict__ bog1,
    const float* __restrict__ gs2, const float* __restrict__ ws2,
    const float* __restrict__ bs2, const float* __restrict__ wsb2,
    const float* __restrict__ wt1, const float* __restrict__ wt2,
    const float* __restrict__ wt3,
    const float* __restrict__ wog2, const float* __restrict__ bog2,
    float* __restrict__ q_o, float* __restrict__ k_o, float* __restrict__ v_o,
    float* __restrict__ g_o, float* __restrict__ og1_o, float* __restrict__ trans_o) {
    // --- LN phase: 32 lanes per row (2 rows per wave), wave-lockstep in-place ---
    {
        int r = t >> 5, l = t & 31;
        float s = 0, s2 = 0;
        for (int k = 0; k < 4; k++) { float x = sm.lna[r][l + 32 * k]; s += x; s2 += x * x; }
        for (int m = 1; m < 32; m <<= 1) { s += __shfl_xor(s, m); s2 += __shfl_xor(s2, m); }
        float mean = s * (1.0f / 128.0f);
        float rs = rsqrtf(s2 * (1.0f / 128.0f) - mean * mean + 1e-5f);
        float cs = 0, cs2 = 0;
        for (int k = 0; k < 4; k++) { float x = sm.cls[r][l + 32 * k]; cs += x; cs2 += x * x; }
        for (int m = 1; m < 32; m <<= 1) { cs += __shfl_xor(cs, m); cs2 += __shfl_xor(cs2, m); }
        float cmean = cs * (1.0f / 128.0f);
        float crs = rsqrtf(cs2 * (1.0f / 128.0f) - cmean * cmean + 1e-5f);
        for (int k = 0; k < 4; k++) {
            int c = l + 32 * k;
            sm.lna[r][c] = (sm.lna[r][c] - mean) * rs;
            float cn = (sm.cls[r][c] - cmean) * crs;
            sm.sn1[r][c] = cn * gs1[c];
            sm.sn2[r][c] = cn * gs2[c];
        }
    }
    __syncthreads();

    const int o = t & 127;
    const int rb = (t >> 7) * 4;  // 4 rows per thread
    float G[4];                   // og2 gate, stays in registers until the epilogue

    { // merged: AdaLN1 + AdaLN2 + og1 + og2 gate (6 weight streams, 24 FMA/c)
        float A1[4] = {0, 0, 0, 0}, B1[4] = {0, 0, 0, 0};
        float A2[4] = {0, 0, 0, 0}, B2[4] = {0, 0, 0, 0};
        float O1[4] = {0, 0, 0, 0}, O2[4] = {0, 0, 0, 0};
        for (int c = 0; c < CC; c++) {
            float w_a1 = ws1[c * CC + o], w_b1 = wsb1[c * CC + o];
            float w_a2 = ws2[c * CC + o], w_b2 = wsb2[c * CC + o];
            float w_o1 = wog1[c * CC + o], w_o2 = wog2[c * CC + o];
#pragma unroll
            for (int r = 0; r < 4; r++) {
                float x1 = sm.sn1[rb + r][c], x2 = sm.sn2[rb + r][c], xc = sm.cls[rb + r][c];
                A1[r] += x1 * w_a1; B1[r] += x1 * w_b1;
                A2[r] += x2 * w_a2; B2[r] += x2 * w_b2;
                O1[r] += xc * w_o1; O2[r] += xc * w_o2;
            }
        }
        float b1 = bs1[o], b2 = bs2[o], bo1 = bog1[o], bo2 = bog2[o];
        for (int r = 0; r < 4; r++) {
            sm.aln1[rb + r][o] = sigm(A1[r] + b1) * sm.lna[rb + r][o] + B1[r];
            sm.a2s[rb + r][o]  = sigm(A2[r] + b2) * sm.lna[rb + r][o] + B2[r];
            og1_o[(n0 + rb + r) * CC + o] = sigm(O1[r] + bo1);
            G[r] = sigm(O2[r] + bo2);
        }
    }
    __syncthreads();

    { // q,k,v,g projections from aln1
        float Aq[4] = {0, 0, 0, 0}, Ak[4] = {0, 0, 0, 0}, Av[4] = {0, 0, 0, 0}, Ag[4] = {0, 0, 0, 0};
        for (int c = 0; c < CC; c++) {
            float wqv = wq[c * CC + o], wkv = wk[c * CC + o], wvv = wv[c * CC + o], wgv = wg[c * CC + o];
#pragma unroll
            for (int r = 0; r < 4; r++) {
                float x = sm.aln1[rb + r][c];
                Aq[r] += x * wqv; Ak[r] += x * wkv; Av[r] += x * wvv; Ag[r] += x * wgv;
            }
        }
        float bqv = bq[o];
        for (int r = 0; r < 4; r++) {
            int n = n0 + rb + r;
            q_o[n * CC + o] = Aq[r] + bqv;
            k_o[n * CC + o] = Ak[r];
            v_o[n * CC + o] = Av[r];
            g_o[n * CC + o] = sigm(Ag[r]);
        }
    }
    { // transition hidden: silu(a2@wt1) * (a2@wt2); thread t owns hidden col t, all 8 rows
        float A[8] = {0, 0, 0, 0, 0, 0, 0, 0};
        for (int c = 0; c < CC; c++) {
            float w = wt1[c * NHID + t];
#pragma unroll
            for (int r = 0; r < 8; r++) A[r] += sm.a2s[r][c] * w;
        }
#pragma unroll
        for (int r = 0; r < 8; r++) { float x = A[r]; sm.hid[r][t] = x * sigm(x); }
        float B[8] = {0, 0, 0, 0, 0, 0, 0, 0};
        for (int c = 0; c < CC; c++) {
            float w = wt2[c * NHID + t];
#pragma unroll
            for (int r = 0; r < 8; r++) B[r] += sm.a2s[r][c] * w;
        }
#pragma unroll
        for (int r = 0; r < 8; r++) sm.hid[r][t] *= B[r];
    }
    __syncthreads();
    { // trans = G * (hid @ wt3)   (G = sigmoid(cl@wog2+bog2), computed in merged loop)
        float A[4] = {0, 0, 0, 0};
        for (int c = 0; c < NHID; c++) {
            float w = wt3[c * CC + o];
#pragma unroll
            for (int r = 0; r < 4; r++) A[r] += sm.hid[rb + r][c] * w;
        }
        for (int r = 0; r < 4; r++)
            trans_o[(n0 + rb + r) * CC + o] = G[r] * A[r];
    }
}

// ---------------------------------------------------------------------------
// First block: a = ql (straight from global).
__global__ __launch_bounds__(256) void k_update_first(
    const float* __restrict__ a_in, const float* __restrict__ cl,
    const float* __restrict__ gs1, const float* __restrict__ ws1,
    const float* __restrict__ bs1, const float* __restrict__ wsb1,
    const float* __restrict__ wq, const float* __restrict__ bq,
    const float* __restrict__ wk, const float* __restrict__ wv,
    const float* __restrict__ wg,
    const float* __restrict__ wog1, const float* __restrict__ bog1,
    const float* __restrict__ gs2, const float* __restrict__ ws2,
    const float* __restrict__ bs2, const float* __restrict__ wsb2,
    const float* __restrict__ wt1, const float* __restrict__ wt2,
    const float* __restrict__ wt3,
    const float* __restrict__ wog2, const float* __restrict__ bog2,
    float* __restrict__ q_o, float* __restrict__ k_o, float* __restrict__ v_o,
    float* __restrict__ g_o, float* __restrict__ og1_o, float* __restrict__ trans_o) {
    __shared__ SmemU sm;
    const int t = threadIdx.x;
    const int n0 = blockIdx.x * R1;
    for (int idx = t; idx < R1 * CC; idx += 256) {
        sm.lna[idx >> 7][idx & 127] = a_in[n0 * CC + idx];
        sm.cls[idx >> 7][idx & 127] = cl[n0 * CC + idx];
    }
    __syncthreads();
    adaln_proj_body(sm, t, n0, gs1, ws1, bs1, wsb1, wq, bq, wk, wv, wg, wog1, bog1,
                    gs2, ws2, bs2, wsb2, wt1, wt2, wt3, wog2, bog2,
                    q_o, k_o, v_o, g_o, og1_o, trans_o);
}

// ---------------------------------------------------------------------------
// Later blocks: fused combine (a = og1*((g*o)@wo)+trans) + AdaLN/projections.
// Everything is row-local, so the prev-block g/og1/trans buffers can be both
// read (phase A) and overwritten (body) by the same workgroup.
__global__ __launch_bounds__(256) void k_update(
    const float* __restrict__ cl,
    const float* __restrict__ g_in, const float* __restrict__ o_in,
    const float* __restrict__ og1_in, const float* __restrict__ trans_in,
    const float* __restrict__ wo_prev,
    const float* __restrict__ gs1, const float* __restrict__ ws1,
    const float* __restrict__ bs1, const float* __restrict__ wsb1,
    const float* __restrict__ wq, const float* __restrict__ bq,
    const float* __restrict__ wk, const float* __restrict__ wv,
    const float* __restrict__ wg,
    const float* __restrict__ wog1, const float* __restrict__ bog1,
    const float* __restrict__ gs2, const float* __restrict__ ws2,
    const float* __restrict__ bs2, const float* __restrict__ wsb2,
    const float* __restrict__ wt1, const float* __restrict__ wt2,
    const float* __restrict__ wt3,
    const float* __restrict__ wog2, const float* __restrict__ bog2,
    float* __restrict__ q_o, float* __restrict__ k_o, float* __restrict__ v_o,
    float* __restrict__ g_o, float* __restrict__ og1_o, float* __restrict__ trans_o) {
    __shared__ SmemU sm;
    const int t = threadIdx.x;
    const int n0 = blockIdx.x * R1;
    // phase A: gos = g*o into aln1-scratch; cl rows
    for (int idx = t; idx < R1 * CC; idx += 256) {
        sm.aln1[idx >> 7][idx & 127] = g_in[n0 * CC + idx] * o_in[n0 * CC + idx];
        sm.cls[idx >> 7][idx & 127] = cl[n0 * CC + idx];
    }
    __syncthreads();
    {
        const int o = t & 127;
        const int rb = (t >> 7) * 4;
        float A[4] = {0, 0, 0, 0};
        for (int c = 0; c < CC; c++) {
            float w = wo_prev[c * CC + o];
#pragma unroll
            for (int r = 0; r < 4; r++) A[r] += sm.aln1[rb + r][c] * w;
        }
        for (int r = 0; r < 4; r++) {
            int n = n0 + rb + r;
            sm.lna[rb + r][o] = og1_in[n * CC + o] * A[r] + trans_in[n * CC + o];
        }
    }
    __syncthreads();
    adaln_proj_body(sm, t, n0, gs1, ws1, bs1, wsb1, wq, bq, wk, wv, wg, wog1, bog1,
                    gs2, ws2, bs2, wsb2, wt1, wt2, wt3, wog2, bog2,
                    q_o, k_o, v_o, g_o, og1_o, trans_o);
}

// ---------------------------------------------------------------------------
// K_attn: one workgroup per (query block, head). 32 queries x <=128 keys.
// q rows held in registers; all LDS traffic is float4 (b128).
__global__ __launch_bounds__(256) void k_attn(const float* __restrict__ q,
                                              const float* __restrict__ k,
                                              const float* __restrict__ v,
                                              const float* __restrict__ pb,
                                              const float* __restrict__ amask,
                                              float* __restrict__ o_out) {
    __shared__ __align__(16) float qs[32][36];
    __shared__ __align__(16) float ks[128][36];
    __shared__ __align__(16) float vs[128][36];
    __shared__ __align__(16) float ps[32][132];
    const int t = threadIdx.x;
    const int qb = blockIdx.x >> 2, h = blockIdx.x & 3;
    const int n0 = qb * 32;
    const int kstart = max(0, qb * 32 - 48);
    const int nk = min(N_ATOM, qb * 32 + 80) - kstart;

    {   // stage q: 32 rows x 8 float4
        int qi = t >> 3, dq = t & 7;
        *(float4*)&qs[qi][dq * 4] = *(const float4*)&q[(n0 + qi) * CC + h * CHD + dq * 4];
    }
    for (int idx = t; idx < 1024; idx += 256) {  // stage k,v: 128 rows x 8 float4
        int kj = idx >> 3, dq = idx & 7;
        int m = kstart + kj;
        float4 kv = {0, 0, 0, 0}, vv = {0, 0, 0, 0};
        if (m < N_ATOM) {
            kv = *(const float4*)&k[m * CC + h * CHD + dq * 4];
            vv = *(const float4*)&v[m * CC + h * CHD + dq * 4];
        }
        *(float4*)&ks[kj][dq * 4] = kv;
        *(float4*)&vs[kj][dq * 4] = vv;
    }
    __syncthreads();

    const int qi = t >> 3, j8 = t & 7;  // 8 threads per query row (same wave)
    float4 qr[8];
#pragma unroll
    for (int dq = 0; dq < 8; dq++) qr[dq] = *(const float4*)&qs[qi][dq * 4];

    const float isc = 0.17677669529663687f;  // 1/sqrt(32)
    const float* pbrow = pb + ((qb * HH + h) * 32 + qi) * 128;
    float lr[16];
    float mx = -1e30f;
#pragma unroll
    for (int jj = 0; jj < 16; jj++) {
        int kj = j8 + 8 * jj;
        float acc = 0;
#pragma unroll
        for (int dq = 0; dq < 8; dq++) {
            float4 kk = *(const float4*)&ks[kj][dq * 4];
            acc += qr[dq].x * kk.x + qr[dq].y * kk.y + qr[dq].z * kk.z + qr[dq].w * kk.w;
        }
        float l = (kj < nk) ? (acc * isc + pbrow[kj] + amask[kstart + kj]) : -1e9f;
        lr[jj] = l;
        mx = fmaxf(mx, l);
    }
    for (int m = 1; m < 8; m <<= 1) mx = fmaxf(mx, __shfl_xor(mx, m));
    float sum = 0;
#pragma unroll
    for (int jj = 0; jj < 16; jj++) { lr[jj] = __expf(lr[jj] - mx); sum += lr[jj]; }
    for (int m = 1; m < 8; m <<= 1) sum += __shfl_xor(sum, m);
    float rd = 1.0f / sum;
#pragma unroll
    for (int jj = 0; jj < 16; jj++) ps[qi][j8 + 8 * jj] = lr[jj] * rd;
    __syncthreads();

    const int d0 = (t & 7) * 4;
    float4 acc = {0, 0, 0, 0};
    for (int kj = 0; kj < 128; kj += 4) {
        float4 pv = *(const float4*)&ps[qi][kj];
        float4 v0 = *(const float4*)&vs[kj][d0];
        float4 v1 = *(const float4*)&vs[kj + 1][d0];
        float4 v2 = *(const float4*)&vs[kj + 2][d0];
        float4 v3 = *(const float4*)&vs[kj + 3][d0];
        acc.x += pv.x * v0.x + pv.y * v1.x + pv.z * v2.x + pv.w * v3.x;
        acc.y += pv.x * v0.y + pv.y * v1.y + pv.z * v2.y + pv.w * v3.y;
        acc.z += pv.x * v0.z + pv.y * v1.z + pv.z * v2.z + pv.w * v3.z;
        acc.w += pv.x * v0.w + pv.y * v1.w + pv.z * v2.w + pv.w * v3.w;
    }
    *(float4*)&o_out[(n0 + qi) * CC + h * CHD + d0] = acc;
}

// ---------------------------------------------------------------------------
// Final combine only (writes d_out): a_new = og1 * ((g*o) @ wo) + trans
__global__ __launch_bounds__(256) void k_combine(const float* __restrict__ g,
                                                 const float* __restrict__ o_in,
                                                 const float* __restrict__ og1,
                                                 const float* __restrict__ trans,
                                                 const float* __restrict__ wo,
                                                 float* __restrict__ a_out) {
    __shared__ float gos[R1][CC];
    const int t = threadIdx.x;
    const int n0 = blockIdx.x * R1;
    for (int idx = t; idx < R1 * CC; idx += 256)
        gos[idx >> 7][idx & 127] = g[n0 * CC + idx] * o_in[n0 * CC + idx];
    __syncthreads();
    const int o = t & 127, rb = (t >> 7) * 4;
    float A[4] = {0, 0, 0, 0};
    for (int c = 0; c < CC; c++) {
        float w = wo[c * CC + o];
#pragma unroll
        for (int r = 0; r < 4; r++) A[r] += gos[rb + r][c] * w;
    }
    for (int r = 0; r < 4; r++) {
        int n = n0 + rb + r;
        a_out[n * CC + o] = og1[n * CC + o] * A[r] + trans[n * CC + o];
    }
}

// ---------------------------------------------------------------------------
extern "C" void kernel_launch(void* const* d_in, const int* in_sizes, int n_in,
                              void* d_out, int out_size, void* d_ws, size_t ws_size,
                              hipStream_t stream) {
    const float* ql   = (const float*)d_in[0];
    const float* cl   = (const float*)d_in[1];
    const float* plm  = (const float*)d_in[2];
    const float* a2t  = (const float*)d_in[3];
    const float* tm   = (const float*)d_in[4];
    const float* ada1_gs  = (const float*)d_in[5];
    const float* ada1_ws  = (const float*)d_in[6];
    const float* ada1_bs  = (const float*)d_in[7];
    const float* ada1_wsb = (const float*)d_in[8];
    const float* wq  = (const float*)d_in[9];
    const float* bq  = (const float*)d_in[10];
    const float* wk  = (const float*)d_in[11];
    const float* wv  = (const float*)d_in[12];
    const float* gz  = (const float*)d_in[13];
    const float* bz  = (const float*)d_in[14];
    const float* wz  = (const float*)d_in[15];
    const float* wg  = (const float*)d_in[16];
    const float* wo  = (const float*)d_in[17];
    const float* wog1 = (const float*)d_in[18];
    const float* bog1 = (const float*)d_in[19];
    const float* ada2_gs  = (const float*)d_in[20];
    const float* ada2_ws  = (const float*)d_in[21];
    const float* ada2_bs  = (const float*)d_in[22];
    const float* ada2_wsb = (const float*)d_in[23];
    const float* wt1 = (const float*)d_in[24];
    const float* wt2 = (const float*)d_in[25];
    const float* wt3 = (const float*)d_in[26];
    const float* wog2 = (const float*)d_in[27];
    const float* bog2 = (const float*)d_in[28];

    const size_t NC = (size_t)N_ATOM * CC;  // 262144
    float* ws = (float*)d_ws;
    float* q_    = ws + 0 * NC;
    float* k_    = ws + 1 * NC;
    float* v_    = ws + 2 * NC;
    float* g_    = ws + 3 * NC;
    float* og1_  = ws + 4 * NC;
    float* tr_   = ws + 5 * NC;
    float* o_    = ws + 6 * NC;
    float* pb3   = ws + 7 * NC;                      // 3 * 1048576 floats
    float* am    = ws + 7 * NC + 3 * PBSTRIDE;       // 2048 floats

    k_amask<<<N_ATOM / 4, 256, 0, stream>>>(a2t, tm, am);
    k_pb3<<<1024, 256, 0, stream>>>(plm, gz, bz, wz, pb3);

    for (int b = 0; b < 3; b++) {
        if (b == 0) {
            k_update_first<<<N_ATOM / R1, 256, 0, stream>>>(
                ql, cl,
                ada1_gs, ada1_ws, ada1_bs, ada1_wsb,
                wq, bq, wk, wv, wg, wog1, bog1,
                ada2_gs, ada2_ws, ada2_bs, ada2_wsb,
                wt1, wt2, wt3, wog2, bog2,
                q_, k_, v_, g_, og1_, tr_);
        } else {
            k_update<<<N_ATOM / R1, 256, 0, stream>>>(
                cl, g_, o_, og1_, tr_, wo + (b - 1) * CC * CC,
                ada1_gs + b * CC, ada1_ws + b * CC * CC, ada1_bs + b * CC, ada1_wsb + b * CC * CC,
                wq + b * CC * CC, bq + b * CC, wk + b * CC * CC, wv + b * CC * CC, wg + b * CC * CC,
                wog1 + b * CC * CC, bog1 + b * CC,
                ada2_gs + b * CC, ada2_ws + b * CC * CC, ada2_bs + b * CC, ada2_wsb + b * CC * CC,
                wt1 + b * CC * NHID, wt2 + b * CC * NHID, wt3 + b * NHID * CC,
                wog2 + b * CC * CC, bog2 + b * CC,
                q_, k_, v_, g_, og1_, tr_);
        }
        k_attn<<<NQB * HH, 256, 0, stream>>>(q_, k_, v_, pb3 + b * PBSTRIDE, am, o_);
    }
    k_combine<<<N_ATOM / R1, 256, 0, stream>>>(g_, o_, og1_, tr_, wo + 2 * CC * CC,
                                               (float*)d_out);
}

// Round 2
// 684.127 us; speedup vs baseline: 1.0819x; 1.0561x over previous
//
#include <hip/hip_runtime.h>
#include <math.h>

#define N_ATOM 2048
#define NTOK   512
#define CC     128
#define CZDIM  16
#define HH     4
#define CHD    32
#define NHID   256
#define NQB    64     // 2048 / 32 query blocks
#define R1     8      // rows per workgroup in update kernels
#define PBSTRIDE 1048576  // 64*4*32*128 floats per block's pair bias

__device__ __forceinline__ float sigm(float x) { return 1.0f / (1.0f + __expf(-x)); }

// ---------------------------------------------------------------------------
// K_pb3 + amask fused.
// blocks [0,1024): pair bias for ALL 3 NB blocks in one pass over the plm window.
// blocks [1024,1536): amask_bias[l] = (sum_i a2t[l,i]*tm[i] - 1) * 1e9
__global__ __launch_bounds__(256) void k_pb3_amask(const float* __restrict__ plm,
                                                   const float* __restrict__ gz,
                                                   const float* __restrict__ bz,
                                                   const float* __restrict__ wz,
                                                   const float* __restrict__ a2t,
                                                   const float* __restrict__ tm,
                                                   float* __restrict__ pb,
                                                   float* __restrict__ amask) {
    if (blockIdx.x >= 1024) {
        int wave = threadIdx.x >> 6, lane = threadIdx.x & 63;
        int l = (blockIdx.x - 1024) * 4 + wave;
        float s = 0.0f;
        for (int i = lane; i < NTOK; i += 64) s += a2t[(size_t)l * NTOK + i] * tm[i];
        for (int m = 1; m < 64; m <<= 1) s += __shfl_xor(s, m);
        if (lane == 0) amask[l] = (s - 1.0f) * 1e9f;
        return;
    }
    int pid = blockIdx.x * 256 + threadIdx.x;  // 64*32*128 total
    int qb = pid >> 12;
    int qi = (pid >> 7) & 31;
    int kj = pid & 127;
    int n = qb * 32 + qi;
    int kstart = max(0, qb * 32 - 48);
    int m = kstart + kj;
    bool valid = (m < N_ATOM);
    float xn[CZDIM];
    if (valid) {
        const float4* p4 = (const float4*)(plm + ((size_t)n * N_ATOM + m) * CZDIM);
        float x[CZDIM];
#pragma unroll
        for (int i = 0; i < 4; i++) {
            float4 v = p4[i];
            x[4 * i] = v.x; x[4 * i + 1] = v.y; x[4 * i + 2] = v.z; x[4 * i + 3] = v.w;
        }
        float s = 0, s2 = 0;
#pragma unroll
        for (int c = 0; c < CZDIM; c++) { s += x[c]; s2 += x[c] * x[c]; }
        float mean = s * (1.0f / 16.0f);
        float rs = rsqrtf(s2 * (1.0f / 16.0f) - mean * mean + 1e-5f);
#pragma unroll
        for (int c = 0; c < CZDIM; c++) xn[c] = (x[c] - mean) * rs;
    }
#pragma unroll
    for (int b = 0; b < 3; b++) {
        float out[HH] = {0, 0, 0, 0};
        if (valid) {
            const float* gzb = gz + b * CZDIM;
            const float* bzb = bz + b * CZDIM;
            const float* wzb = wz + b * CZDIM * HH;
#pragma unroll
            for (int c = 0; c < CZDIM; c++) {
                float z = xn[c] * gzb[c] + bzb[c];
#pragma unroll
                for (int h = 0; h < HH; h++) out[h] += z * wzb[c * HH + h];
            }
        }
#pragma unroll
        for (int h = 0; h < HH; h++)
            pb[b * PBSTRIDE + (((qb * HH + h) * 32 + qi) << 7) + kj] = out[h];
    }
}

// ---------------------------------------------------------------------------
// Shared-memory layout + fused AdaLN/projection body (512-thread version).
// 8 waves/wg -> 2 waves/SIMD at grid=256: doubles latency hiding vs 256-thr.
struct SmemU {
    float lna[R1][CC];   // raw a on entry to body; LN(a) after LN phase
    float sn1[R1][CC];   // LN(cl)*gs1
    float sn2[R1][CC];   // LN(cl)*gs2
    float cls[R1][CC];   // raw cl
    float aln1[R1][CC];  // AdaLN1 output (also used as g*o scratch in phase A)
    float a2s[R1][CC];   // AdaLN2 output
    float hid[R1][NHID]; // SwiGLU hidden
};

__device__ __forceinline__ void adaln_proj_body(
    SmemU& sm, int t, int n0,
    const float* __restrict__ gs1, const float* __restrict__ ws1,
    const float* __restrict__ bs1, const float* __restrict__ wsb1,
    const float* __restrict__ wq, const float* __restrict__ bq,
    const float* __restrict__ wk, const float* __restrict__ wv,
    const float* __restrict__ wg,
    const float* __restrict__ wog1, const float* __restrict__ bog1,
    const float* __restrict__ gs2, const float* __restrict__ ws2,
    const float* __restrict__ bs2, const float* __restrict__ wsb2,
    const float* __restrict__ wt1, const float* __restrict__ wt2,
    const float* __restrict__ wt3,
    const float* __restrict__ wog2, const float* __restrict__ bog2,
    float* __restrict__ q_o, float* __restrict__ k_o, float* __restrict__ v_o,
    float* __restrict__ g_o, float* __restrict__ og1_o, float* __restrict__ trans_o) {
    // --- LN phase: one wave per row, 64 lanes x 2 elements ---
    {
        int r = t >> 6, l = t & 63;
        float s = 0, s2 = 0;
        for (int k = 0; k < 2; k++) { float x = sm.lna[r][l + 64 * k]; s += x; s2 += x * x; }
        for (int m = 1; m < 64; m <<= 1) { s += __shfl_xor(s, m); s2 += __shfl_xor(s2, m); }
        float mean = s * (1.0f / 128.0f);
        float rs = rsqrtf(s2 * (1.0f / 128.0f) - mean * mean + 1e-5f);
        float cs = 0, cs2 = 0;
        for (int k = 0; k < 2; k++) { float x = sm.cls[r][l + 64 * k]; cs += x; cs2 += x * x; }
        for (int m = 1; m < 64; m <<= 1) { cs += __shfl_xor(cs, m); cs2 += __shfl_xor(cs2, m); }
        float cmean = cs * (1.0f / 128.0f);
        float crs = rsqrtf(cs2 * (1.0f / 128.0f) - cmean * cmean + 1e-5f);
        for (int k = 0; k < 2; k++) {
            int c = l + 64 * k;
            sm.lna[r][c] = (sm.lna[r][c] - mean) * rs;
            float cn = (sm.cls[r][c] - cmean) * crs;
            sm.sn1[r][c] = cn * gs1[c];
            sm.sn2[r][c] = cn * gs2[c];
        }
    }
    __syncthreads();

    const int o = t & 127;
    const int rb = (t >> 7) * 2;  // 2 rows per thread (4 row-groups)
    float G[2];                   // og2 gate, stays in registers until the epilogue

    { // merged: AdaLN1 + AdaLN2 + og1 + og2 gate (6 weight streams, 12 FMA/c)
        float A1[2] = {0, 0}, B1[2] = {0, 0};
        float A2[2] = {0, 0}, B2[2] = {0, 0};
        float O1[2] = {0, 0}, O2[2] = {0, 0};
        for (int c = 0; c < CC; c++) {
            float w_a1 = ws1[c * CC + o], w_b1 = wsb1[c * CC + o];
            float w_a2 = ws2[c * CC + o], w_b2 = wsb2[c * CC + o];
            float w_o1 = wog1[c * CC + o], w_o2 = wog2[c * CC + o];
#pragma unroll
            for (int r = 0; r < 2; r++) {
                float x1 = sm.sn1[rb + r][c], x2 = sm.sn2[rb + r][c], xc = sm.cls[rb + r][c];
                A1[r] += x1 * w_a1; B1[r] += x1 * w_b1;
                A2[r] += x2 * w_a2; B2[r] += x2 * w_b2;
                O1[r] += xc * w_o1; O2[r] += xc * w_o2;
            }
        }
        float b1 = bs1[o], b2 = bs2[o], bo1 = bog1[o], bo2 = bog2[o];
        for (int r = 0; r < 2; r++) {
            sm.aln1[rb + r][o] = sigm(A1[r] + b1) * sm.lna[rb + r][o] + B1[r];
            sm.a2s[rb + r][o]  = sigm(A2[r] + b2) * sm.lna[rb + r][o] + B2[r];
            og1_o[(n0 + rb + r) * CC + o] = sigm(O1[r] + bo1);
            G[r] = sigm(O2[r] + bo2);
        }
    }
    __syncthreads();

    { // q,k,v,g projections from aln1
        float Aq[2] = {0, 0}, Ak[2] = {0, 0}, Av[2] = {0, 0}, Ag[2] = {0, 0};
        for (int c = 0; c < CC; c++) {
            float wqv = wq[c * CC + o], wkv = wk[c * CC + o], wvv = wv[c * CC + o], wgv = wg[c * CC + o];
#pragma unroll
            for (int r = 0; r < 2; r++) {
                float x = sm.aln1[rb + r][c];
                Aq[r] += x * wqv; Ak[r] += x * wkv; Av[r] += x * wvv; Ag[r] += x * wgv;
            }
        }
        float bqv = bq[o];
        for (int r = 0; r < 2; r++) {
            int n = n0 + rb + r;
            q_o[n * CC + o] = Aq[r] + bqv;
            k_o[n * CC + o] = Ak[r];
            v_o[n * CC + o] = Av[r];
            g_o[n * CC + o] = sigm(Ag[r]);
        }
    }
    { // transition hidden: silu(a2@wt1) * (a2@wt2); col = t&255, 4 rows per thread
        const int ht = t & 255, hb = (t >> 8) * 4;
        float A[4] = {0, 0, 0, 0};
        for (int c = 0; c < CC; c++) {
            float w = wt1[c * NHID + ht];
#pragma unroll
            for (int r = 0; r < 4; r++) A[r] += sm.a2s[hb + r][c] * w;
        }
#pragma unroll
        for (int r = 0; r < 4; r++) { float x = A[r]; sm.hid[hb + r][ht] = x * sigm(x); }
        float B[4] = {0, 0, 0, 0};
        for (int c = 0; c < CC; c++) {
            float w = wt2[c * NHID + ht];
#pragma unroll
            for (int r = 0; r < 4; r++) B[r] += sm.a2s[hb + r][c] * w;
        }
#pragma unroll
        for (int r = 0; r < 4; r++) sm.hid[hb + r][ht] *= B[r];
    }
    __syncthreads();
    { // trans = G * (hid @ wt3)   (G = sigmoid(cl@wog2+bog2), computed in merged loop)
        float A[2] = {0, 0};
        for (int c = 0; c < NHID; c++) {
            float w = wt3[c * CC + o];
#pragma unroll
            for (int r = 0; r < 2; r++) A[r] += sm.hid[rb + r][c] * w;
        }
        for (int r = 0; r < 2; r++)
            trans_o[(n0 + rb + r) * CC + o] = G[r] * A[r];
    }
}

// ---------------------------------------------------------------------------
// First block: a = ql (straight from global).
__global__ __launch_bounds__(512) void k_update_first(
    const float* __restrict__ a_in, const float* __restrict__ cl,
    const float* __restrict__ gs1, const float* __restrict__ ws1,
    const float* __restrict__ bs1, const float* __restrict__ wsb1,
    const float* __restrict__ wq, const float* __restrict__ bq,
    const float* __restrict__ wk, const float* __restrict__ wv,
    const float* __restrict__ wg,
    const float* __restrict__ wog1, const float* __restrict__ bog1,
    const float* __restrict__ gs2, const float* __restrict__ ws2,
    const float* __restrict__ bs2, const float* __restrict__ wsb2,
    const float* __restrict__ wt1, const float* __restrict__ wt2,
    const float* __restrict__ wt3,
    const float* __restrict__ wog2, const float* __restrict__ bog2,
    float* __restrict__ q_o, float* __restrict__ k_o, float* __restrict__ v_o,
    float* __restrict__ g_o, float* __restrict__ og1_o, float* __restrict__ trans_o) {
    __shared__ SmemU sm;
    const int t = threadIdx.x;
    const int n0 = blockIdx.x * R1;
    if (t < 256)
        ((float4*)sm.lna)[t] = ((const float4*)(a_in + (size_t)n0 * CC))[t];
    else
        ((float4*)sm.cls)[t - 256] = ((const float4*)(cl + (size_t)n0 * CC))[t - 256];
    __syncthreads();
    adaln_proj_body(sm, t, n0, gs1, ws1, bs1, wsb1, wq, bq, wk, wv, wg, wog1, bog1,
                    gs2, ws2, bs2, wsb2, wt1, wt2, wt3, wog2, bog2,
                    q_o, k_o, v_o, g_o, og1_o, trans_o);
}

// ---------------------------------------------------------------------------
// Later blocks: fused combine (a = og1*((g*o)@wo)+trans) + AdaLN/projections.
__global__ __launch_bounds__(512) void k_update(
    const float* __restrict__ cl,
    const float* __restrict__ g_in, const float* __restrict__ o_in,
    const float* __restrict__ og1_in, const float* __restrict__ trans_in,
    const float* __restrict__ wo_prev,
    const float* __restrict__ gs1, const float* __restrict__ ws1,
    const float* __restrict__ bs1, const float* __restrict__ wsb1,
    const float* __restrict__ wq, const float* __restrict__ bq,
    const float* __restrict__ wk, const float* __restrict__ wv,
    const float* __restrict__ wg,
    const float* __restrict__ wog1, const float* __restrict__ bog1,
    const float* __restrict__ gs2, const float* __restrict__ ws2,
    const float* __restrict__ bs2, const float* __restrict__ wsb2,
    const float* __restrict__ wt1, const float* __restrict__ wt2,
    const float* __restrict__ wt3,
    const float* __restrict__ wog2, const float* __restrict__ bog2,
    float* __restrict__ q_o, float* __restrict__ k_o, float* __restrict__ v_o,
    float* __restrict__ g_o, float* __restrict__ og1_o, float* __restrict__ trans_o) {
    __shared__ SmemU sm;
    const int t = threadIdx.x;
    const int n0 = blockIdx.x * R1;
    // phase A: gos = g*o into aln1-scratch; cl rows
    if (t < 256) {
        float4 gv = ((const float4*)(g_in + (size_t)n0 * CC))[t];
        float4 ov = ((const float4*)(o_in + (size_t)n0 * CC))[t];
        float4 p; p.x = gv.x * ov.x; p.y = gv.y * ov.y; p.z = gv.z * ov.z; p.w = gv.w * ov.w;
        ((float4*)sm.aln1)[t] = p;
    } else {
        ((float4*)sm.cls)[t - 256] = ((const float4*)(cl + (size_t)n0 * CC))[t - 256];
    }
    __syncthreads();
    {
        const int o = t & 127;
        const int rb = (t >> 7) * 2;
        float A[2] = {0, 0};
        for (int c = 0; c < CC; c++) {
            float w = wo_prev[c * CC + o];
#pragma unroll
            for (int r = 0; r < 2; r++) A[r] += sm.aln1[rb + r][c] * w;
        }
        for (int r = 0; r < 2; r++) {
            int n = n0 + rb + r;
            sm.lna[rb + r][o] = og1_in[n * CC + o] * A[r] + trans_in[n * CC + o];
        }
    }
    __syncthreads();
    adaln_proj_body(sm, t, n0, gs1, ws1, bs1, wsb1, wq, bq, wk, wv, wg, wog1, bog1,
                    gs2, ws2, bs2, wsb2, wt1, wt2, wt3, wog2, bog2,
                    q_o, k_o, v_o, g_o, og1_o, trans_o);
}

// ---------------------------------------------------------------------------
// K_attn: one workgroup per (query block, head). 32 queries x <=128 keys.
// 512 threads (2 waves/SIMD): 16 threads per query row.
__global__ __launch_bounds__(512) void k_attn(const float* __restrict__ q,
                                              const float* __restrict__ k,
                                              const float* __restrict__ v,
                                              const float* __restrict__ pb,
                                              const float* __restrict__ amask,
                                              float* __restrict__ o_out) {
    __shared__ __align__(16) float qs[32][36];
    __shared__ __align__(16) float ks[128][36];
    __shared__ __align__(16) float vs[128][36];
    __shared__ __align__(16) float ps[32][132];
    const int t = threadIdx.x;
    const int qb = blockIdx.x >> 2, h = blockIdx.x & 3;
    const int n0 = qb * 32;
    const int kstart = max(0, qb * 32 - 48);
    const int nk = min(N_ATOM, qb * 32 + 80) - kstart;

    if (t < 256) {  // stage q: 32 rows x 8 float4
        int qi = t >> 3, dq = t & 7;
        *(float4*)&qs[qi][dq * 4] = *(const float4*)&q[(n0 + qi) * CC + h * CHD + dq * 4];
    }
    for (int idx = t; idx < 1024; idx += 512) {  // stage k,v: 128 rows x 8 float4
        int kj = idx >> 3, dq = idx & 7;
        int m = kstart + kj;
        float4 kv = {0, 0, 0, 0}, vv = {0, 0, 0, 0};
        if (m < N_ATOM) {
            kv = *(const float4*)&k[m * CC + h * CHD + dq * 4];
            vv = *(const float4*)&v[m * CC + h * CHD + dq * 4];
        }
        *(float4*)&ks[kj][dq * 4] = kv;
        *(float4*)&vs[kj][dq * 4] = vv;
    }
    __syncthreads();

    const int qi = t >> 4, j16 = t & 15;  // 16 threads per query row (same wave)
    float4 qr[8];
#pragma unroll
    for (int dq = 0; dq < 8; dq++) qr[dq] = *(const float4*)&qs[qi][dq * 4];

    const float isc = 0.17677669529663687f;  // 1/sqrt(32)
    const float* pbrow = pb + ((qb * HH + h) * 32 + qi) * 128;
    float lr[8];
    float mx = -1e30f;
#pragma unroll
    for (int jj = 0; jj < 8; jj++) {
        int kj = j16 + 16 * jj;
        float acc = 0;
#pragma unroll
        for (int dq = 0; dq < 8; dq++) {
            float4 kk = *(const float4*)&ks[kj][dq * 4];
            acc += qr[dq].x * kk.x + qr[dq].y * kk.y + qr[dq].z * kk.z + qr[dq].w * kk.w;
        }
        float l = (kj < nk) ? (acc * isc + pbrow[kj] + amask[kstart + kj]) : -1e9f;
        lr[jj] = l;
        mx = fmaxf(mx, l);
    }
    for (int m = 1; m < 16; m <<= 1) mx = fmaxf(mx, __shfl_xor(mx, m));
    float sum = 0;
#pragma unroll
    for (int jj = 0; jj < 8; jj++) { lr[jj] = __expf(lr[jj] - mx); sum += lr[jj]; }
    for (int m = 1; m < 16; m <<= 1) sum += __shfl_xor(sum, m);
    float rd = 1.0f / sum;
#pragma unroll
    for (int jj = 0; jj < 8; jj++) ps[qi][j16 + 16 * jj] = lr[jj] * rd;
    __syncthreads();

    const int d0 = (t & 15) * 2;  // 16 threads cover 32 dims as float2
    float2 acc = {0, 0};
    for (int kj = 0; kj < 128; kj += 4) {
        float4 pv = *(const float4*)&ps[qi][kj];
        float2 v0 = *(const float2*)&vs[kj][d0];
        float2 v1 = *(const float2*)&vs[kj + 1][d0];
        float2 v2 = *(const float2*)&vs[kj + 2][d0];
        float2 v3 = *(const float2*)&vs[kj + 3][d0];
        acc.x += pv.x * v0.x + pv.y * v1.x + pv.z * v2.x + pv.w * v3.x;
        acc.y += pv.x * v0.y + pv.y * v1.y + pv.z * v2.y + pv.w * v3.y;
    }
    *(float2*)&o_out[(n0 + qi) * CC + h * CHD + d0] = acc;
}

// ---------------------------------------------------------------------------
// Final combine only (writes d_out): a_new = og1 * ((g*o) @ wo) + trans
__global__ __launch_bounds__(512) void k_combine(const float* __restrict__ g,
                                                 const float* __restrict__ o_in,
                                                 const float* __restrict__ og1,
                                                 const float* __restrict__ trans,
                                                 const float* __restrict__ wo,
                                                 float* __restrict__ a_out) {
    __shared__ float gos[R1][CC];
    const int t = threadIdx.x;
    const int n0 = blockIdx.x * R1;
    if (t < 256) {
        float4 gv = ((const float4*)(g + (size_t)n0 * CC))[t];
        float4 ov = ((const float4*)(o_in + (size_t)n0 * CC))[t];
        float4 p; p.x = gv.x * ov.x; p.y = gv.y * ov.y; p.z = gv.z * ov.z; p.w = gv.w * ov.w;
        ((float4*)gos)[t] = p;
    }
    __syncthreads();
    const int o = t & 127, rb = (t >> 7) * 2;
    float A[2] = {0, 0};
    for (int c = 0; c < CC; c++) {
        float w = wo[c * CC + o];
#pragma unroll
        for (int r = 0; r < 2; r++) A[r] += gos[rb + r][c] * w;
    }
    for (int r = 0; r < 2; r++) {
        int n = n0 + rb + r;
        a_out[n * CC + o] = og1[n * CC + o] * A[r] + trans[n * CC + o];
    }
}

// ---------------------------------------------------------------------------
extern "C" void kernel_launch(void* const* d_in, const int* in_sizes, int n_in,
                              void* d_out, int out_size, void* d_ws, size_t ws_size,
                              hipStream_t stream) {
    const float* ql   = (const float*)d_in[0];
    const float* cl   = (const float*)d_in[1];
    const float* plm  = (const float*)d_in[2];
    const float* a2t  = (const float*)d_in[3];
    const float* tm   = (const float*)d_in[4];
    const float* ada1_gs  = (const float*)d_in[5];
    const float* ada1_ws  = (const float*)d_in[6];
    const float* ada1_bs  = (const float*)d_in[7];
    const float* ada1_wsb = (const float*)d_in[8];
    const float* wq  = (const float*)d_in[9];
    const float* bq  = (const float*)d_in[10];
    const float* wk  = (const float*)d_in[11];
    const float* wv  = (const float*)d_in[12];
    const float* gz  = (const float*)d_in[13];
    const float* bz  = (const float*)d_in[14];
    const float* wz  = (const float*)d_in[15];
    const float* wg  = (const float*)d_in[16];
    const float* wo  = (const float*)d_in[17];
    const float* wog1 = (const float*)d_in[18];
    const float* bog1 = (const float*)d_in[19];
    const float* ada2_gs  = (const float*)d_in[20];
    const float* ada2_ws  = (const float*)d_in[21];
    const float* ada2_bs  = (const float*)d_in[22];
    const float* ada2_wsb = (const float*)d_in[23];
    const float* wt1 = (const float*)d_in[24];
    const float* wt2 = (const float*)d_in[25];
    const float* wt3 = (const float*)d_in[26];
    const float* wog2 = (const float*)d_in[27];
    const float* bog2 = (const float*)d_in[28];

    const size_t NC = (size_t)N_ATOM * CC;  // 262144
    float* ws = (float*)d_ws;
    float* q_    = ws + 0 * NC;
    float* k_    = ws + 1 * NC;
    float* v_    = ws + 2 * NC;
    float* g_    = ws + 3 * NC;
    float* og1_  = ws + 4 * NC;
    float* tr_   = ws + 5 * NC;
    float* o_    = ws + 6 * NC;
    float* pb3   = ws + 7 * NC;                      // 3 * 1048576 floats
    float* am    = ws + 7 * NC + 3 * PBSTRIDE;       // 2048 floats

    k_pb3_amask<<<1536, 256, 0, stream>>>(plm, gz, bz, wz, a2t, tm, pb3, am);

    for (int b = 0; b < 3; b++) {
        if (b == 0) {
            k_update_first<<<N_ATOM / R1, 512, 0, stream>>>(
                ql, cl,
                ada1_gs, ada1_ws, ada1_bs, ada1_wsb,
                wq, bq, wk, wv, wg, wog1, bog1,
                ada2_gs, ada2_ws, ada2_bs, ada2_wsb,
                wt1, wt2, wt3, wog2, bog2,
                q_, k_, v_, g_, og1_, tr_);
        } else {
            k_update<<<N_ATOM / R1, 512, 0, stream>>>(
                cl, g_, o_, og1_, tr_, wo + (b - 1) * CC * CC,
                ada1_gs + b * CC, ada1_ws + b * CC * CC, ada1_bs + b * CC, ada1_wsb + b * CC * CC,
                wq + b * CC * CC, bq + b * CC, wk + b * CC * CC, wv + b * CC * CC, wg + b * CC * CC,
                wog1 + b * CC * CC, bog1 + b * CC,
                ada2_gs + b * CC, ada2_ws + b * CC * CC, ada2_bs + b * CC, ada2_wsb + b * CC * CC,
                wt1 + b * CC * NHID, wt2 + b * CC * NHID, wt3 + b * NHID * CC,
                wog2 + b * CC * CC, bog2 + b * CC,
                q_, k_, v_, g_, og1_, tr_);
        }
        k_attn<<<NQB * HH, 512, 0, stream>>>(q_, k_, v_, pb3 + b * PBSTRIDE, am, o_);
    }
    k_combine<<<N_ATOM / R1, 512, 0, stream>>>(g_, o_, og1_, tr_, wo + 2 * CC * CC,
                                               (float*)d_out);
}